// Round 2
// baseline (655.562 us; speedup 1.0000x reference)
//
#include <hip/hip_runtime.h>
#include <float.h>
#include <math.h>

// Problem constants (from reference)
#define N_DB   200000
#define D_EMB  512
#define K      32

// Kernel-1 config: 512 blocks x 512 threads
#define NBLK   512
#define TPB    512
#define WAVES  (TPB / 64)                    // 8 waves/block
#define RPB    ((N_DB + NBLK - 1) / NBLK)    // 391 rows per block
#define SELREG ((RPB + 63) / 64)             // 7 regs/lane for selection
#define NCAND  (NBLK * K)                    // 16384 candidates

// Kernel-2 config
#define TPB2   512
#define WAVES2 (TPB2 / 64)                   // 8
#define CPW    (NCAND / WAVES2)              // 2048 candidates per wave
#define CREG   (CPW / 64)                    // 32 regs per lane

typedef float v4f __attribute__((ext_vector_type(4)));

// ---------------------------------------------------------------------------
// Kernel 1: streaming squared-distance computation + wave-0 register top-32.
// v3: A/B vs v2 — plain (cache-allocating) loads instead of nontemporal.
// Theory: both v1 (8-load) and v2 (16-load) structures landed within 0.2%,
// so the distance phase is pinned by the NT read path, not issue rate.
// Everything else is bit-identical to v2 (same association tree, same
// selection), so output bits are unchanged.
// ---------------------------------------------------------------------------
__global__ __launch_bounds__(TPB, 4) void knn_dist_topk(
    const float* __restrict__ x,
    const float* __restrict__ X_emb,
    float* __restrict__ cand_d,
    int*   __restrict__ cand_i)
{
    __shared__ float xs[D_EMB];
    __shared__ float dists[RPB];

    const int tid  = threadIdx.x;
    const int wid  = tid >> 6;
    const int lane = tid & 63;
    const int base = blockIdx.x * RPB;
    const int rows = min(RPB, N_DB - base);

    // Stage query vector in LDS
    for (int i = tid; i < D_EMB; i += TPB) xs[i] = x[i];
    __syncthreads();

    const v4f* xq = (const v4f*)xs;
    const v4f q0 = xq[lane];
    const v4f q1 = xq[lane + 64];

    // Contiguous per-wave row range
    const int per_wave = (rows + WAVES - 1) / WAVES;
    const int w0 = min(wid * per_wave, rows);
    const int w1 = min(w0 + per_wave, rows);

    int r = w0;
    for (; r + 8 <= w1; r += 8) {
        const float* rp = X_emb + (size_t)(base + r) * D_EMB;
        v4f a[8], b[8];
        #pragma unroll
        for (int i = 0; i < 8; ++i) {
            const v4f* p = (const v4f*)(rp + (size_t)i * D_EMB);
            a[i] = p[lane];
            b[i] = p[lane + 64];
        }
        float s[8];
        #pragma unroll
        for (int i = 0; i < 8; ++i) {
            float t = 0.f, d;
            d = a[i].x - q0.x; t = fmaf(d, d, t);
            d = a[i].y - q0.y; t = fmaf(d, d, t);
            d = a[i].z - q0.z; t = fmaf(d, d, t);
            d = a[i].w - q0.w; t = fmaf(d, d, t);
            d = b[i].x - q1.x; t = fmaf(d, d, t);
            d = b[i].y - q1.y; t = fmaf(d, d, t);
            d = b[i].z - q1.z; t = fmaf(d, d, t);
            d = b[i].w - q1.w; t = fmaf(d, d, t);
            s[i] = t;
        }
        // Transpose-combine reduction. Level 1: offset 32 (bit5).
        float qv[4];
        {
            const bool hi = (lane & 32) != 0;
            #pragma unroll
            for (int j = 0; j < 4; ++j) {
                float u = hi ? s[2 * j + 1] : s[2 * j];
                float w = __shfl_xor(hi ? s[2 * j] : s[2 * j + 1], 32);
                qv[j] = u + w;
            }
        }
        // Level 2: offset 16 (bit4).
        float uv[2];
        {
            const bool hi = (lane & 16) != 0;
            #pragma unroll
            for (int j = 0; j < 2; ++j) {
                float u = hi ? qv[2 * j + 1] : qv[2 * j];
                float w = __shfl_xor(hi ? qv[2 * j] : qv[2 * j + 1], 16);
                uv[j] = u + w;
            }
        }
        // Level 3: offset 8 (bit3), then plain butterfly over bits 2,1,0.
        {
            const bool hi = (lane & 8) != 0;
            float u = hi ? uv[1] : uv[0];
            float w = __shfl_xor(hi ? uv[0] : uv[1], 8);
            float v = u + w;
            v += __shfl_xor(v, 4);
            v += __shfl_xor(v, 2);
            v += __shfl_xor(v, 1);
            if ((lane & 7) == 0) {
                const int row = ((lane >> 3) & 1) * 4 + ((lane >> 4) & 1) * 2
                              + ((lane >> 5) & 1);
                dists[r + row] = v;   // squared distance; sqrt deferred to k2
            }
        }
    }
    // Remainder rows: single-row path (same butterfly tree).
    for (; r < w1; ++r) {
        const v4f* p = (const v4f*)(X_emb + (size_t)(base + r) * D_EMB);
        v4f a = p[lane];
        v4f b = p[lane + 64];
        float s = 0.f, d;
        d = a.x - q0.x; s = fmaf(d, d, s);
        d = a.y - q0.y; s = fmaf(d, d, s);
        d = a.z - q0.z; s = fmaf(d, d, s);
        d = a.w - q0.w; s = fmaf(d, d, s);
        d = b.x - q1.x; s = fmaf(d, d, s);
        d = b.y - q1.y; s = fmaf(d, d, s);
        d = b.z - q1.z; s = fmaf(d, d, s);
        d = b.w - q1.w; s = fmaf(d, d, s);
        #pragma unroll
        for (int off = 32; off > 0; off >>= 1) s += __shfl_xor(s, off);
        if (lane == 0) dists[r] = s;
    }
    __syncthreads();

    // Wave-0-only register-resident top-32 (barrier-free)
    if (wid == 0) {
        float dv[SELREG];
        int   di[SELREG];
        #pragma unroll
        for (int j = 0; j < SELREG; ++j) {
            const int idx = j * 64 + lane;
            dv[j] = (idx < rows) ? dists[idx] : FLT_MAX;
            di[j] = base + idx;
        }
        for (int it = 0; it < K; ++it) {
            float bv = dv[0];
            int   bi = di[0];
            #pragma unroll
            for (int j = 1; j < SELREG; ++j) {
                if (dv[j] < bv || (dv[j] == bv && di[j] < bi)) { bv = dv[j]; bi = di[j]; }
            }
            #pragma unroll
            for (int off = 32; off > 0; off >>= 1) {
                float ov = __shfl_xor(bv, off);
                int   oi = __shfl_xor(bi, off);
                if (ov < bv || (ov == bv && oi < bi)) { bv = ov; bi = oi; }
            }
            if (lane == 0) {
                cand_d[blockIdx.x * K + it] = bv;
                cand_i[blockIdx.x * K + it] = bi;
            }
            #pragma unroll
            for (int j = 0; j < SELREG; ++j) if (di[j] == bi) dv[j] = FLT_MAX;
        }
    }
}

// ---------------------------------------------------------------------------
// Kernel 2: two-stage register-resident reduction of 16384 candidates,
// then gather rows/classes/distances. Tie-break everywhere: lowest db index.
// ---------------------------------------------------------------------------
__global__ __launch_bounds__(TPB2) void knn_final(
    const float* __restrict__ X_emb,
    const int*   __restrict__ X_cls,
    const float* __restrict__ cand_d,
    const int*   __restrict__ cand_i,
    float* __restrict__ out)
{
    __shared__ float sd[WAVES2 * K];
    __shared__ int   si[WAVES2 * K];
    __shared__ float fd[K];
    __shared__ int   fi[K];

    const int tid  = threadIdx.x;
    const int wid  = tid >> 6;
    const int lane = tid & 63;

    // Stage A: each wave owns 2048 candidates in registers, emits its top-32
    {
        float dv[CREG];
        int   di[CREG];
        const int cbase = wid * CPW;
        #pragma unroll
        for (int j = 0; j < CREG; ++j) {
            const int c = cbase + j * 64 + lane;
            dv[j] = cand_d[c];
            di[j] = cand_i[c];
        }
        for (int it = 0; it < K; ++it) {
            float bv = dv[0];
            int   bi = di[0];
            #pragma unroll
            for (int j = 1; j < CREG; ++j) {
                if (dv[j] < bv || (dv[j] == bv && di[j] < bi)) { bv = dv[j]; bi = di[j]; }
            }
            #pragma unroll
            for (int off = 32; off > 0; off >>= 1) {
                float ov = __shfl_xor(bv, off);
                int   oi = __shfl_xor(bi, off);
                if (ov < bv || (ov == bv && oi < bi)) { bv = ov; bi = oi; }
            }
            if (lane == 0) { sd[wid * K + it] = bv; si[wid * K + it] = bi; }
            #pragma unroll
            for (int j = 0; j < CREG; ++j) if (di[j] == bi) dv[j] = FLT_MAX;
        }
    }
    __syncthreads();

    // Stage B: wave 0 reduces 256 survivors to the final 32 (ascending)
    if (wid == 0) {
        float ev[4];
        int   ei[4];
        #pragma unroll
        for (int j = 0; j < 4; ++j) {
            const int idx = j * 64 + lane;
            ev[j] = sd[idx];
            ei[j] = si[idx];
        }
        for (int it = 0; it < K; ++it) {
            float bv = ev[0];
            int   bi = ei[0];
            #pragma unroll
            for (int j = 1; j < 4; ++j) {
                if (ev[j] < bv || (ev[j] == bv && ei[j] < bi)) { bv = ev[j]; bi = ei[j]; }
            }
            #pragma unroll
            for (int off = 32; off > 0; off >>= 1) {
                float ov = __shfl_xor(bv, off);
                int   oi = __shfl_xor(bi, off);
                if (ov < bv || (ov == bv && oi < bi)) { bv = ov; bi = oi; }
            }
            if (lane == 0) { fd[it] = sqrtf(bv); fi[it] = bi; }
            #pragma unroll
            for (int j = 0; j < 4; ++j) if (ei[j] == bi) ev[j] = FLT_MAX;
        }
    }
    __syncthreads();

    // Gather: out layout = emb[32*512] | cls[32] | dist[32]
    v4f* out_emb = (v4f*)out;
    for (int rr = wid; rr < K; rr += WAVES2) {
        const v4f* p = (const v4f*)(X_emb + (size_t)fi[rr] * D_EMB);
        out_emb[rr * 128 + lane]      = p[lane];
        out_emb[rr * 128 + lane + 64] = p[lane + 64];
    }
    if (tid < K) {
        out[K * D_EMB + tid]     = (float)X_cls[fi[tid]];
        out[K * D_EMB + K + tid] = fd[tid];
    }
}

extern "C" void kernel_launch(void* const* d_in, const int* in_sizes, int n_in,
                              void* d_out, int out_size, void* d_ws, size_t ws_size,
                              hipStream_t stream) {
    const float* x     = (const float*)d_in[0];
    const float* X_emb = (const float*)d_in[1];
    const int*   X_cls = (const int*)d_in[2];
    // d_in[3] is k == 32 (hard-coded)

    float* cand_d = (float*)d_ws;
    int*   cand_i = (int*)((char*)d_ws + NCAND * sizeof(float));

    knn_dist_topk<<<NBLK, TPB, 0, stream>>>(x, X_emb, cand_d, cand_i);
    knn_final<<<1, TPB2, 0, stream>>>(X_emb, X_cls, cand_d, cand_i, (float*)d_out);
}

// Round 3
// 619.809 us; speedup vs baseline: 1.0577x; 1.0577x over previous
//
#include <hip/hip_runtime.h>
#include <float.h>
#include <math.h>

// Problem constants (from reference)
#define N_DB   200000
#define D_EMB  512
#define K      32

// Kernel-1 config: 512 blocks x 512 threads
#define NBLK   512
#define TPB    512
#define WAVES  (TPB / 64)                    // 8 waves/block
#define RPB    ((N_DB + NBLK - 1) / NBLK)    // 391 rows per block
#define SELREG ((RPB + 63) / 64)             // 7 regs/lane for selection
#define NCAND  (NBLK * K)                    // 16384 candidates

// Kernel-2 config
#define TPB2   512
#define WAVES2 (TPB2 / 64)                   // 8
#define CPW    (NCAND / WAVES2)              // 2048 candidates per wave
#define CREG   (CPW / 64)                    // 32 regs per lane

typedef float v4f __attribute__((ext_vector_type(4)));

// ---------------------------------------------------------------------------
// Kernel 1: streaming squared-distance computation + wave-0 register top-32.
// v4 = v2 (revert): NONTEMPORAL loads are essential — round-2 A/B showed
// plain (cache-allocating) loads cost +35 us on the 409.6 MB single-pass
// stream (L3 can't hold it; poison fills evict it anyway). Two different
// NT schedules (8 vs 16 loads in flight) measured identical, so the
// distance phase is pinned at the NT read-path ceiling: keep NT, keep the
// cheap 10-shuffle transpose-combine reduction.
// Selection phase: wave 0 only — dists cached in 7 regs/lane, 32 barrier-free
// shfl-argmin passes (tie-break: lowest db index).
// ---------------------------------------------------------------------------
__global__ __launch_bounds__(TPB, 4) void knn_dist_topk(
    const float* __restrict__ x,
    const float* __restrict__ X_emb,
    float* __restrict__ cand_d,
    int*   __restrict__ cand_i)
{
    __shared__ float xs[D_EMB];
    __shared__ float dists[RPB];

    const int tid  = threadIdx.x;
    const int wid  = tid >> 6;
    const int lane = tid & 63;
    const int base = blockIdx.x * RPB;
    const int rows = min(RPB, N_DB - base);

    // Stage query vector in LDS
    for (int i = tid; i < D_EMB; i += TPB) xs[i] = x[i];
    __syncthreads();

    const v4f* xq = (const v4f*)xs;
    const v4f q0 = xq[lane];
    const v4f q1 = xq[lane + 64];

    // Contiguous per-wave row range
    const int per_wave = (rows + WAVES - 1) / WAVES;
    const int w0 = min(wid * per_wave, rows);
    const int w1 = min(w0 + per_wave, rows);

    int r = w0;
    for (; r + 8 <= w1; r += 8) {
        const float* rp = X_emb + (size_t)(base + r) * D_EMB;
        v4f a[8], b[8];
        #pragma unroll
        for (int i = 0; i < 8; ++i) {
            const v4f* p = (const v4f*)(rp + (size_t)i * D_EMB);
            a[i] = __builtin_nontemporal_load(&p[lane]);
            b[i] = __builtin_nontemporal_load(&p[lane + 64]);
        }
        float s[8];
        #pragma unroll
        for (int i = 0; i < 8; ++i) {
            float t = 0.f, d;
            d = a[i].x - q0.x; t = fmaf(d, d, t);
            d = a[i].y - q0.y; t = fmaf(d, d, t);
            d = a[i].z - q0.z; t = fmaf(d, d, t);
            d = a[i].w - q0.w; t = fmaf(d, d, t);
            d = b[i].x - q1.x; t = fmaf(d, d, t);
            d = b[i].y - q1.y; t = fmaf(d, d, t);
            d = b[i].z - q1.z; t = fmaf(d, d, t);
            d = b[i].w - q1.w; t = fmaf(d, d, t);
            s[i] = t;
        }
        // Transpose-combine reduction. Level 1: offset 32 (bit5).
        float qv[4];
        {
            const bool hi = (lane & 32) != 0;
            #pragma unroll
            for (int j = 0; j < 4; ++j) {
                float u = hi ? s[2 * j + 1] : s[2 * j];
                float w = __shfl_xor(hi ? s[2 * j] : s[2 * j + 1], 32);
                qv[j] = u + w;
            }
        }
        // Level 2: offset 16 (bit4).
        float uv[2];
        {
            const bool hi = (lane & 16) != 0;
            #pragma unroll
            for (int j = 0; j < 2; ++j) {
                float u = hi ? qv[2 * j + 1] : qv[2 * j];
                float w = __shfl_xor(hi ? qv[2 * j] : qv[2 * j + 1], 16);
                uv[j] = u + w;
            }
        }
        // Level 3: offset 8 (bit3), then plain butterfly over bits 2,1,0.
        {
            const bool hi = (lane & 8) != 0;
            float u = hi ? uv[1] : uv[0];
            float w = __shfl_xor(hi ? uv[0] : uv[1], 8);
            float v = u + w;
            v += __shfl_xor(v, 4);
            v += __shfl_xor(v, 2);
            v += __shfl_xor(v, 1);
            if ((lane & 7) == 0) {
                const int row = ((lane >> 3) & 1) * 4 + ((lane >> 4) & 1) * 2
                              + ((lane >> 5) & 1);
                dists[r + row] = v;   // squared distance; sqrt deferred to k2
            }
        }
    }
    // Remainder rows: single-row path (same butterfly tree).
    for (; r < w1; ++r) {
        const v4f* p = (const v4f*)(X_emb + (size_t)(base + r) * D_EMB);
        v4f a = __builtin_nontemporal_load(&p[lane]);
        v4f b = __builtin_nontemporal_load(&p[lane + 64]);
        float s = 0.f, d;
        d = a.x - q0.x; s = fmaf(d, d, s);
        d = a.y - q0.y; s = fmaf(d, d, s);
        d = a.z - q0.z; s = fmaf(d, d, s);
        d = a.w - q0.w; s = fmaf(d, d, s);
        d = b.x - q1.x; s = fmaf(d, d, s);
        d = b.y - q1.y; s = fmaf(d, d, s);
        d = b.z - q1.z; s = fmaf(d, d, s);
        d = b.w - q1.w; s = fmaf(d, d, s);
        #pragma unroll
        for (int off = 32; off > 0; off >>= 1) s += __shfl_xor(s, off);
        if (lane == 0) dists[r] = s;
    }
    __syncthreads();

    // Wave-0-only register-resident top-32 (barrier-free)
    if (wid == 0) {
        float dv[SELREG];
        int   di[SELREG];
        #pragma unroll
        for (int j = 0; j < SELREG; ++j) {
            const int idx = j * 64 + lane;
            dv[j] = (idx < rows) ? dists[idx] : FLT_MAX;
            di[j] = base + idx;
        }
        for (int it = 0; it < K; ++it) {
            float bv = dv[0];
            int   bi = di[0];
            #pragma unroll
            for (int j = 1; j < SELREG; ++j) {
                if (dv[j] < bv || (dv[j] == bv && di[j] < bi)) { bv = dv[j]; bi = di[j]; }
            }
            #pragma unroll
            for (int off = 32; off > 0; off >>= 1) {
                float ov = __shfl_xor(bv, off);
                int   oi = __shfl_xor(bi, off);
                if (ov < bv || (ov == bv && oi < bi)) { bv = ov; bi = oi; }
            }
            if (lane == 0) {
                cand_d[blockIdx.x * K + it] = bv;
                cand_i[blockIdx.x * K + it] = bi;
            }
            #pragma unroll
            for (int j = 0; j < SELREG; ++j) if (di[j] == bi) dv[j] = FLT_MAX;
        }
    }
}

// ---------------------------------------------------------------------------
// Kernel 2: two-stage register-resident reduction of 16384 candidates,
// then gather rows/classes/distances. Tie-break everywhere: lowest db index.
// ---------------------------------------------------------------------------
__global__ __launch_bounds__(TPB2) void knn_final(
    const float* __restrict__ X_emb,
    const int*   __restrict__ X_cls,
    const float* __restrict__ cand_d,
    const int*   __restrict__ cand_i,
    float* __restrict__ out)
{
    __shared__ float sd[WAVES2 * K];
    __shared__ int   si[WAVES2 * K];
    __shared__ float fd[K];
    __shared__ int   fi[K];

    const int tid  = threadIdx.x;
    const int wid  = tid >> 6;
    const int lane = tid & 63;

    // Stage A: each wave owns 2048 candidates in registers, emits its top-32
    {
        float dv[CREG];
        int   di[CREG];
        const int cbase = wid * CPW;
        #pragma unroll
        for (int j = 0; j < CREG; ++j) {
            const int c = cbase + j * 64 + lane;
            dv[j] = cand_d[c];
            di[j] = cand_i[c];
        }
        for (int it = 0; it < K; ++it) {
            float bv = dv[0];
            int   bi = di[0];
            #pragma unroll
            for (int j = 1; j < CREG; ++j) {
                if (dv[j] < bv || (dv[j] == bv && di[j] < bi)) { bv = dv[j]; bi = di[j]; }
            }
            #pragma unroll
            for (int off = 32; off > 0; off >>= 1) {
                float ov = __shfl_xor(bv, off);
                int   oi = __shfl_xor(bi, off);
                if (ov < bv || (ov == bv && oi < bi)) { bv = ov; bi = oi; }
            }
            if (lane == 0) { sd[wid * K + it] = bv; si[wid * K + it] = bi; }
            #pragma unroll
            for (int j = 0; j < CREG; ++j) if (di[j] == bi) dv[j] = FLT_MAX;
        }
    }
    __syncthreads();

    // Stage B: wave 0 reduces 256 survivors to the final 32 (ascending)
    if (wid == 0) {
        float ev[4];
        int   ei[4];
        #pragma unroll
        for (int j = 0; j < 4; ++j) {
            const int idx = j * 64 + lane;
            ev[j] = sd[idx];
            ei[j] = si[idx];
        }
        for (int it = 0; it < K; ++it) {
            float bv = ev[0];
            int   bi = ei[0];
            #pragma unroll
            for (int j = 1; j < 4; ++j) {
                if (ev[j] < bv || (ev[j] == bv && ei[j] < bi)) { bv = ev[j]; bi = ei[j]; }
            }
            #pragma unroll
            for (int off = 32; off > 0; off >>= 1) {
                float ov = __shfl_xor(bv, off);
                int   oi = __shfl_xor(bi, off);
                if (ov < bv || (ov == bv && oi < bi)) { bv = ov; bi = oi; }
            }
            if (lane == 0) { fd[it] = sqrtf(bv); fi[it] = bi; }
            #pragma unroll
            for (int j = 0; j < 4; ++j) if (ei[j] == bi) ev[j] = FLT_MAX;
        }
    }
    __syncthreads();

    // Gather: out layout = emb[32*512] | cls[32] | dist[32]
    v4f* out_emb = (v4f*)out;
    for (int rr = wid; rr < K; rr += WAVES2) {
        const v4f* p = (const v4f*)(X_emb + (size_t)fi[rr] * D_EMB);
        out_emb[rr * 128 + lane]      = p[lane];
        out_emb[rr * 128 + lane + 64] = p[lane + 64];
    }
    if (tid < K) {
        out[K * D_EMB + tid]     = (float)X_cls[fi[tid]];
        out[K * D_EMB + K + tid] = fd[tid];
    }
}

extern "C" void kernel_launch(void* const* d_in, const int* in_sizes, int n_in,
                              void* d_out, int out_size, void* d_ws, size_t ws_size,
                              hipStream_t stream) {
    const float* x     = (const float*)d_in[0];
    const float* X_emb = (const float*)d_in[1];
    const int*   X_cls = (const int*)d_in[2];
    // d_in[3] is k == 32 (hard-coded)

    float* cand_d = (float*)d_ws;
    int*   cand_i = (int*)((char*)d_ws + NCAND * sizeof(float));

    knn_dist_topk<<<NBLK, TPB, 0, stream>>>(x, X_emb, cand_d, cand_i);
    knn_final<<<1, TPB2, 0, stream>>>(X_emb, X_cls, cand_d, cand_i, (float*)d_out);
}